// Round 1
// baseline (635.720 us; speedup 1.0000x reference)
//
#include <hip/hip_runtime.h>
#include <math.h>

constexpr float EPS = 1e-5f;
constexpr float SCALE = 0.08838834764831845f; // 1/sqrt(128)

// ================= tiled fp32 GEMM, optional fused LayerNorm epilogue ========
// out[m][j] = (LN over j of) sum_d A[m][d]*W[j][d] + bias[j],  j in [0,128)
template<int KDIM, bool DO_LN>
__global__ __launch_bounds__(256) void gemm_ln_kernel(
    const float* __restrict__ A, const float* __restrict__ W,
    const float* __restrict__ bias, const float* __restrict__ gamma,
    const float* __restrict__ beta, float* __restrict__ out)
{
    constexpr int TM = 64, KT = 16;
    __shared__ __align__(16) float As[TM][KT + 4];   // stride 20: f4-aligned rows
    __shared__ __align__(16) float Ws[KT][132];      // k-major, padded
    __shared__ float Ps[TM][129];
    __shared__ float mu_s[TM], rs_s[TM];

    const int tid = threadIdx.x;
    const int m0  = blockIdx.x * TM;
    const int tm  = (tid >> 4) * 4;        // 4 token rows
    const int tjb = (tid & 15) * 4;        // j in [tjb,tjb+4) and [tjb+64,tjb+68)

    float acc[4][8];
#pragma unroll
    for (int i = 0; i < 4; i++)
#pragma unroll
        for (int j = 0; j < 8; j++) acc[i][j] = 0.f;

    for (int kk = 0; kk < KDIM; kk += KT) {
        { // stage A tile (64 x 16), one float4 per thread
            int r = tid >> 2, c = (tid & 3) * 4;
            float4 a4 = *(const float4*)&A[(size_t)(m0 + r) * KDIM + kk + c];
            *(float4*)&As[r][c] = a4;
        }
#pragma unroll
        for (int i = 0; i < 2; i++) { // stage W tile (16 x 128) transposed
            int f = tid + i * 256;
            int r = f >> 2, c = (f & 3) * 4;
            float4 w4 = *(const float4*)&W[(size_t)r * KDIM + kk + c];
            Ws[c + 0][r] = w4.x; Ws[c + 1][r] = w4.y;
            Ws[c + 2][r] = w4.z; Ws[c + 3][r] = w4.w;
        }
        __syncthreads();
#pragma unroll
        for (int d4 = 0; d4 < KT; d4 += 4) {
            float aa[4][4];
#pragma unroll
            for (int i = 0; i < 4; i++) {
                float4 av = *(const float4*)&As[tm + i][d4];
                aa[i][0] = av.x; aa[i][1] = av.y; aa[i][2] = av.z; aa[i][3] = av.w;
            }
            float4 w0[4], w1[4];
#pragma unroll
            for (int dd = 0; dd < 4; dd++) {
                w0[dd] = *(const float4*)&Ws[d4 + dd][tjb];
                w1[dd] = *(const float4*)&Ws[d4 + dd][tjb + 64];
            }
#pragma unroll
            for (int dd = 0; dd < 4; dd++) {
#pragma unroll
                for (int i = 0; i < 4; i++) {
                    float a = aa[i][dd];
                    acc[i][0] += a * w0[dd].x; acc[i][1] += a * w0[dd].y;
                    acc[i][2] += a * w0[dd].z; acc[i][3] += a * w0[dd].w;
                    acc[i][4] += a * w1[dd].x; acc[i][5] += a * w1[dd].y;
                    acc[i][6] += a * w1[dd].z; acc[i][7] += a * w1[dd].w;
                }
            }
        }
        __syncthreads();
    }

    // bias + park tile in LDS
    float bb[8];
#pragma unroll
    for (int j = 0; j < 8; j++) bb[j] = bias[(j < 4) ? (tjb + j) : (tjb + 64 + j - 4)];
#pragma unroll
    for (int i = 0; i < 4; i++)
#pragma unroll
        for (int j = 0; j < 8; j++) {
            int col = (j < 4) ? (tjb + j) : (tjb + 64 + j - 4);
            Ps[tm + i][col] = acc[i][j] + bb[j];
        }
    __syncthreads();

    if (DO_LN) {
        if (tid < TM) {
            float s = 0.f, s2 = 0.f;
            for (int j = 0; j < 128; j++) { float x = Ps[tid][j]; s += x; s2 += x * x; }
            float mu = s * (1.f / 128.f);
            float var = s2 * (1.f / 128.f) - mu * mu;
            mu_s[tid] = mu; rs_s[tid] = rsqrtf(var + EPS);
        }
        __syncthreads();
        for (int idx = tid; idx < TM * 128; idx += 256) {
            int m = idx >> 7, j = idx & 127;
            out[(size_t)(m0 + m) * 128 + j] = (Ps[m][j] - mu_s[m]) * rs_s[m] * gamma[j] + beta[j];
        }
    } else {
        for (int idx = tid; idx < TM * 128; idx += 256) {
            int m = idx >> 7, j = idx & 127;
            out[(size_t)(m0 + m) * 128 + j] = Ps[m][j];
        }
    }
}

// ================= slots init: mu + exp(log_sigma)*noise =====================
__global__ __launch_bounds__(256) void init_slots_kernel(
    const float* __restrict__ noise, const float* __restrict__ mu,
    const float* __restrict__ ls, float* __restrict__ slots)
{
    int idx = blockIdx.x * 256 + threadIdx.x;   // 49152 total
    int r = idx % 384;
    slots[idx] = mu[r] + expf(ls[r]) * noise[idx];
}

// ================= per-row LN(slots) then q = s @ Wq^T + bq ==================
__global__ __launch_bounds__(128) void lnq_kernel(
    const float* __restrict__ slots, const float* __restrict__ g_s,
    const float* __restrict__ b_s, const float* __restrict__ Wq,
    const float* __restrict__ bq, float* __restrict__ q)
{
    __shared__ float s_l[128];
    __shared__ float red[4];
    int row = blockIdx.x, tid = threadIdx.x;
    float x = slots[row * 128 + tid];
    float s = x, s2 = x * x;
#pragma unroll
    for (int off = 32; off >= 1; off >>= 1) {
        s += __shfl_down(s, off, 64); s2 += __shfl_down(s2, off, 64);
    }
    if ((tid & 63) == 0) { red[tid >> 6] = s; red[2 + (tid >> 6)] = s2; }
    __syncthreads();
    float S = red[0] + red[1], S2 = red[2] + red[3];
    float mu = S * (1.f / 128.f);
    float rs = rsqrtf(S2 * (1.f / 128.f) - mu * mu + EPS);
    s_l[tid] = (x - mu) * rs * g_s[tid] + b_s[tid];
    __syncthreads();
    const float4* wr = (const float4*)&Wq[(size_t)tid * 128];
    float a = bq[tid];
#pragma unroll 8
    for (int d4 = 0; d4 < 32; d4++) {
        float4 w = wr[d4];
        a += s_l[4 * d4] * w.x + s_l[4 * d4 + 1] * w.y
           + s_l[4 * d4 + 2] * w.z + s_l[4 * d4 + 3] * w.w;
    }
    q[row * 128 + tid] = a;
}

// ================= fused attention: logits -> softmax(K) -> updates ==========
__global__ __launch_bounds__(256) void attn_kernel(
    const float* __restrict__ q, const float* __restrict__ kbuf,
    const float* __restrict__ vbuf, float* __restrict__ updates,
    float* __restrict__ attn_out, int write_attn)
{
    __shared__ float q_l[3][128];
    __shared__ float kv_l[64][129];
    __shared__ float lg_l[3][64];
    __shared__ float w_l[3][64];
    const int b = blockIdx.y, n0 = blockIdx.x * 64, tid = threadIdx.x;

    for (int idx = tid; idx < 384; idx += 256)
        q_l[idx >> 7][idx & 127] = q[b * 384 + idx];

    const float4* kg = (const float4*)&kbuf[((size_t)b * 1024 + n0) * 128];
    for (int idx = tid; idx < 64 * 32; idx += 256) {
        float4 t = kg[idx];
        int n = idx >> 5, c = (idx & 31) * 4;
        kv_l[n][c] = t.x; kv_l[n][c + 1] = t.y; kv_l[n][c + 2] = t.z; kv_l[n][c + 3] = t.w;
    }
    __syncthreads();

    if (tid < 192) {
        int kslot = tid >> 6, n = tid & 63;
        float lg = 0.f;
#pragma unroll 8
        for (int d = 0; d < 128; d++) lg += q_l[kslot][d] * kv_l[n][d];
        lg_l[kslot][n] = lg * SCALE;
    }
    __syncthreads();

    if (tid < 64) { // softmax over the 3 slots for token n=tid
        float l0 = lg_l[0][tid], l1 = lg_l[1][tid], l2 = lg_l[2][tid];
        float m = fmaxf(l0, fmaxf(l1, l2));
        float e0 = expf(l0 - m), e1 = expf(l1 - m), e2 = expf(l2 - m);
        float inv = 1.f / (e0 + e1 + e2);
        w_l[0][tid] = e0 * inv; w_l[1][tid] = e1 * inv; w_l[2][tid] = e2 * inv;
        if (write_attn) {
            attn_out[b * 3072 + n0 + tid]        = e0 * inv;
            attn_out[b * 3072 + 1024 + n0 + tid] = e1 * inv;
            attn_out[b * 3072 + 2048 + n0 + tid] = e2 * inv;
        }
    }
    const float4* vg = (const float4*)&vbuf[((size_t)b * 1024 + n0) * 128];
    for (int idx = tid; idx < 64 * 32; idx += 256) {
        float4 t = vg[idx];
        int n = idx >> 5, c = (idx & 31) * 4;
        kv_l[n][c] = t.x; kv_l[n][c + 1] = t.y; kv_l[n][c + 2] = t.z; kv_l[n][c + 3] = t.w;
    }
    __syncthreads();

    if (tid < 128) {
        float p0 = 0.f, p1 = 0.f, p2 = 0.f;
#pragma unroll 8
        for (int n = 0; n < 64; n++) {
            float vv = kv_l[n][tid];
            p0 += w_l[0][n] * vv; p1 += w_l[1][n] * vv; p2 += w_l[2][n] * vv;
        }
        atomicAdd(&updates[(b * 3 + 0) * 128 + tid], p0);
        atomicAdd(&updates[(b * 3 + 1) * 128 + tid], p1);
        atomicAdd(&updates[(b * 3 + 2) * 128 + tid], p2);
    }
}

// ================= fused GRU cell + LN + MLP residual ========================
__global__ __launch_bounds__(128) void gru_mlp_kernel(
    const float* __restrict__ slots_in, const float* __restrict__ updates,
    const float* __restrict__ Wih, const float* __restrict__ bih,
    const float* __restrict__ Whh, const float* __restrict__ bhh,
    const float* __restrict__ g_m, const float* __restrict__ b_m,
    const float* __restrict__ W1, const float* __restrict__ b1,
    const float* __restrict__ W2, const float* __restrict__ b2,
    float* __restrict__ slots_out)
{
    __shared__ float u_l[128], h_l[128], n_l[128], hid_l[256];
    __shared__ float red[4];
    const int row = blockIdx.x, tid = threadIdx.x;

    float hprev = slots_in[row * 128 + tid];
    u_l[tid] = updates[row * 128 + tid];
    h_l[tid] = hprev;
    __syncthreads();

    float ir = bih[tid], iz = bih[128 + tid], in_ = bih[256 + tid];
    float hr = bhh[tid], hz = bhh[128 + tid], hn = bhh[256 + tid];
    const float4* wi0 = (const float4*)&Wih[(size_t)tid * 128];
    const float4* wi1 = (const float4*)&Wih[(size_t)(128 + tid) * 128];
    const float4* wi2 = (const float4*)&Wih[(size_t)(256 + tid) * 128];
    const float4* wh0 = (const float4*)&Whh[(size_t)tid * 128];
    const float4* wh1 = (const float4*)&Whh[(size_t)(128 + tid) * 128];
    const float4* wh2 = (const float4*)&Whh[(size_t)(256 + tid) * 128];
#pragma unroll 4
    for (int d4 = 0; d4 < 32; d4++) {
        float u0 = u_l[4 * d4], u1 = u_l[4 * d4 + 1], u2 = u_l[4 * d4 + 2], u3 = u_l[4 * d4 + 3];
        float h0 = h_l[4 * d4], h1 = h_l[4 * d4 + 1], h2 = h_l[4 * d4 + 2], h3 = h_l[4 * d4 + 3];
        float4 w;
        w = wi0[d4]; ir  += u0 * w.x + u1 * w.y + u2 * w.z + u3 * w.w;
        w = wi1[d4]; iz  += u0 * w.x + u1 * w.y + u2 * w.z + u3 * w.w;
        w = wi2[d4]; in_ += u0 * w.x + u1 * w.y + u2 * w.z + u3 * w.w;
        w = wh0[d4]; hr  += h0 * w.x + h1 * w.y + h2 * w.z + h3 * w.w;
        w = wh1[d4]; hz  += h0 * w.x + h1 * w.y + h2 * w.z + h3 * w.w;
        w = wh2[d4]; hn  += h0 * w.x + h1 * w.y + h2 * w.z + h3 * w.w;
    }
    float r = 1.f / (1.f + expf(-(ir + hr)));
    float z = 1.f / (1.f + expf(-(iz + hz)));
    float nn = tanhf(in_ + r * hn);
    float hnew = (1.f - z) * nn + z * hprev;

    // LayerNorm(hnew) across the 128 threads
    float s = hnew, s2 = hnew * hnew;
#pragma unroll
    for (int off = 32; off >= 1; off >>= 1) {
        s += __shfl_down(s, off, 64); s2 += __shfl_down(s2, off, 64);
    }
    if ((tid & 63) == 0) { red[tid >> 6] = s; red[2 + (tid >> 6)] = s2; }
    __syncthreads();
    float S = red[0] + red[1], S2 = red[2] + red[3];
    float mu = S * (1.f / 128.f);
    float rs = rsqrtf(S2 * (1.f / 128.f) - mu * mu + EPS);
    n_l[tid] = (hnew - mu) * rs * g_m[tid] + b_m[tid];
    __syncthreads();

    // MLP layer 1 (H -> 2H) + exact GELU
    float a0 = b1[tid], a1 = b1[128 + tid];
    const float4* w1a = (const float4*)&W1[(size_t)tid * 128];
    const float4* w1b = (const float4*)&W1[(size_t)(128 + tid) * 128];
#pragma unroll 4
    for (int d4 = 0; d4 < 32; d4++) {
        float x0 = n_l[4 * d4], x1 = n_l[4 * d4 + 1], x2 = n_l[4 * d4 + 2], x3 = n_l[4 * d4 + 3];
        float4 wa = w1a[d4], wb = w1b[d4];
        a0 += x0 * wa.x + x1 * wa.y + x2 * wa.z + x3 * wa.w;
        a1 += x0 * wb.x + x1 * wb.y + x2 * wb.z + x3 * wb.w;
    }
    a0 = 0.5f * a0 * (1.f + erff(a0 * 0.70710678118654752f));
    a1 = 0.5f * a1 * (1.f + erff(a1 * 0.70710678118654752f));
    hid_l[tid] = a0; hid_l[128 + tid] = a1;
    __syncthreads();

    // MLP layer 2 (2H -> H) + residual
    float o = b2[tid];
    const float4* w2r = (const float4*)&W2[(size_t)tid * 256];
#pragma unroll 4
    for (int d4 = 0; d4 < 64; d4++) {
        float4 w = w2r[d4];
        o += hid_l[4 * d4] * w.x + hid_l[4 * d4 + 1] * w.y
           + hid_l[4 * d4 + 2] * w.z + hid_l[4 * d4 + 3] * w.w;
    }
    slots_out[row * 128 + tid] = hnew + o;
}

// ============================================================================
extern "C" void kernel_launch(void* const* d_in, const int* in_sizes, int n_in,
                              void* d_out, int out_size, void* d_ws, size_t ws_size,
                              hipStream_t stream)
{
    const float* patch   = (const float*)d_in[0];
    const float* noise   = (const float*)d_in[1];
    const float* slot_mu = (const float*)d_in[2];
    const float* slot_ls = (const float*)d_in[3];
    const float* Wp = (const float*)d_in[4];  const float* bp = (const float*)d_in[5];
    const float* g_in = (const float*)d_in[6]; const float* b_in = (const float*)d_in[7];
    const float* Wq = (const float*)d_in[8];  const float* bq = (const float*)d_in[9];
    const float* Wk = (const float*)d_in[10]; const float* bk = (const float*)d_in[11];
    const float* Wv = (const float*)d_in[12]; const float* bv = (const float*)d_in[13];
    const float* Wih = (const float*)d_in[14]; const float* bih = (const float*)d_in[15];
    const float* Whh = (const float*)d_in[16]; const float* bhh = (const float*)d_in[17];
    const float* g_s = (const float*)d_in[18]; const float* b_s = (const float*)d_in[19];
    const float* W1 = (const float*)d_in[20]; const float* b1 = (const float*)d_in[21];
    const float* W2 = (const float*)d_in[22]; const float* b2 = (const float*)d_in[23];
    const float* g_m = (const float*)d_in[24]; const float* b_m = (const float*)d_in[25];

    float* ws    = (float*)d_ws;
    float* lnbuf = ws;                         // 131072 x 128
    float* kbuf  = ws + 16777216;              // 131072 x 128
    float* vbuf  = ws + 2 * 16777216;          // 131072 x 128
    float* slots = ws + 3 * 16777216;          // 384 x 128
    float* qbuf  = slots + 49152;
    float* upd   = qbuf + 49152;

    float* out_slots = (float*)d_out;          // (B,K,H) = 49152
    float* out_attn  = (float*)d_out + 49152;  // (B,K,N) = 393216

    gemm_ln_kernel<192, true ><<<2048, 256, 0, stream>>>(patch, Wp, bp, g_in, b_in, lnbuf);
    gemm_ln_kernel<128, false><<<2048, 256, 0, stream>>>(lnbuf, Wk, bk, nullptr, nullptr, kbuf);
    gemm_ln_kernel<128, false><<<2048, 256, 0, stream>>>(lnbuf, Wv, bv, nullptr, nullptr, vbuf);
    init_slots_kernel<<<192, 256, 0, stream>>>(noise, slot_mu, slot_ls, slots);

    for (int it = 0; it < 3; it++) {
        lnq_kernel<<<384, 128, 0, stream>>>(slots, g_s, b_s, Wq, bq, qbuf);
        hipMemsetAsync(upd, 0, 49152 * sizeof(float), stream);
        attn_kernel<<<dim3(16, 128), 256, 0, stream>>>(qbuf, kbuf, vbuf, upd, out_attn,
                                                       it == 2 ? 1 : 0);
        gru_mlp_kernel<<<384, 128, 0, stream>>>(slots, upd, Wih, bih, Whh, bhh,
                                                g_m, b_m, W1, b1, W2, b2,
                                                (it == 2) ? out_slots : slots);
    }
}

// Round 3
// 492.132 us; speedup vs baseline: 1.2918x; 1.2918x over previous
//
#include <hip/hip_runtime.h>
#include <math.h>

constexpr float EPS = 1e-5f;
constexpr float SCALE = 0.08838834764831845f; // 1/sqrt(128)

using f32x4  = __attribute__((ext_vector_type(4))) float;
using bf16x8 = __attribute__((ext_vector_type(8))) short;
using us8    = __attribute__((ext_vector_type(8))) unsigned short;

__device__ __forceinline__ unsigned short f2b_rne(float f) {
    unsigned int x = __float_as_uint(f);
    return (unsigned short)((x + 0x7fffu + ((x >> 16) & 1u)) >> 16);
}
__device__ __forceinline__ float b2f(unsigned short u) {
    return __uint_as_float(((unsigned int)u) << 16);
}

// ================= one-time weight split: fp32 -> (hi, lo) bf16 planes =======
// Wp (24576) | Wk (16384) | Wv (16384) packed contiguously.
__global__ __launch_bounds__(256) void split_weights_kernel(
    const float* __restrict__ Wp, const float* __restrict__ Wk,
    const float* __restrict__ Wv, unsigned short* __restrict__ hi,
    unsigned short* __restrict__ lo)
{
    int idx = blockIdx.x * 256 + threadIdx.x; // 57344 total
    float v;
    if (idx < 24576)      v = Wp[idx];
    else if (idx < 40960) v = Wk[idx - 24576];
    else                  v = Wv[idx - 40960];
    unsigned int bits = __float_as_uint(v);
    hi[idx] = (unsigned short)(bits >> 16);
    lo[idx] = f2b_rne(v - __uint_as_float(bits & 0xffff0000u));
}

// ============== split-precision bf16 MFMA GEMM: out = A @ W^T + bias =========
// Each fp32 operand = hi + lo (bf16); product via 3 MFMAs (hh + hl + lh) ->
// ~2^-17 relative error, effectively fp32. Tile 128x128, BK=32, 4 waves.
// A_PRESPLIT: A given as hi/lo bf16 planes; else fp32, split while staging.
// OUT_SPLIT: store hi/lo bf16 planes; else fp32.  DO_LN: LayerNorm epilogue.
template<int KDIM, bool A_PRESPLIT, bool DO_LN, bool OUT_SPLIT>
__global__ __launch_bounds__(256, 2) void gemm_split_kernel(
    const void* __restrict__ Av, const unsigned short* __restrict__ Alo,
    const unsigned short* __restrict__ Bhi, const unsigned short* __restrict__ Blo,
    const float* __restrict__ bias, const float* __restrict__ gamma,
    const float* __restrict__ beta, float* __restrict__ outf,
    unsigned short* __restrict__ out_hi, unsigned short* __restrict__ out_lo)
{
    __shared__ __align__(16) unsigned short Ah[128 * 32], Al[128 * 32];
    __shared__ __align__(16) unsigned short Bh[128 * 32], Bl[128 * 32];

    const int tid  = threadIdx.x;
    const int lane = tid & 63, wave = tid >> 6;
    const int ln15 = lane & 15, quad = lane >> 4;
    const int m0   = blockIdx.x * 128;
    const int wrow = wave * 32;

    f32x4 acc[2][8];
#pragma unroll
    for (int mt = 0; mt < 2; mt++)
#pragma unroll
        for (int nt = 0; nt < 8; nt++)
#pragma unroll
            for (int r = 0; r < 4; r++) acc[mt][nt][r] = 0.f;

    for (int kk = 0; kk < KDIM; kk += 32) {
        // ---- stage A tile (128 x 32) hi/lo ----
#pragma unroll
        for (int c = tid; c < 512; c += 256) {
            int m = c >> 2, ko = (c & 3) * 8;
            if (A_PRESPLIT) {
                size_t off = (size_t)(m0 + m) * KDIM + kk + ko;
                *(us8*)&Ah[c * 8] = *(const us8*)((const unsigned short*)Av + off);
                *(us8*)&Al[c * 8] = *(const us8*)(Alo + off);
            } else {
                const float* src = (const float*)Av + (size_t)(m0 + m) * KDIM + kk + ko;
                float4 x = *(const float4*)src;
                float4 y = *(const float4*)(src + 4);
                float vv[8] = {x.x, x.y, x.z, x.w, y.x, y.y, y.z, y.w};
                us8 h, l;
#pragma unroll
                for (int j = 0; j < 8; j++) {
                    unsigned int bits = __float_as_uint(vv[j]);
                    h[j] = (unsigned short)(bits >> 16);
                    l[j] = f2b_rne(vv[j] - __uint_as_float(bits & 0xffff0000u));
                }
                *(us8*)&Ah[c * 8] = h;
                *(us8*)&Al[c * 8] = l;
            }
        }
        // ---- stage B tile = W rows (128 x 32), pre-split ----
#pragma unroll
        for (int c = tid; c < 512; c += 256) {
            int n = c >> 2, ko = (c & 3) * 8;
            size_t off = (size_t)n * KDIM + kk + ko;
            *(us8*)&Bh[c * 8] = *(const us8*)(Bhi + off);
            *(us8*)&Bl[c * 8] = *(const us8*)(Blo + off);
        }
        __syncthreads();

        bf16x8 ah[2], al[2];
#pragma unroll
        for (int mt = 0; mt < 2; mt++) {
            int o = (wrow + mt * 16 + ln15) * 32 + quad * 8;
            ah[mt] = *(const bf16x8*)&Ah[o];
            al[mt] = *(const bf16x8*)&Al[o];
        }
#pragma unroll
        for (int nt = 0; nt < 8; nt++) {
            int o = (nt * 16 + ln15) * 32 + quad * 8;
            bf16x8 bh = *(const bf16x8*)&Bh[o];
            bf16x8 bl = *(const bf16x8*)&Bl[o];
#pragma unroll
            for (int mt = 0; mt < 2; mt++) {
                acc[mt][nt] = __builtin_amdgcn_mfma_f32_16x16x32_bf16(ah[mt], bh, acc[mt][nt], 0, 0, 0);
                acc[mt][nt] = __builtin_amdgcn_mfma_f32_16x16x32_bf16(ah[mt], bl, acc[mt][nt], 0, 0, 0);
                acc[mt][nt] = __builtin_amdgcn_mfma_f32_16x16x32_bf16(al[mt], bh, acc[mt][nt], 0, 0, 0);
            }
        }
        __syncthreads();
    }

    // ---- epilogue: bias (+ LN) -> store ----
    float bb[8], gg[8], be[8];
#pragma unroll
    for (int nt = 0; nt < 8; nt++) {
        int col = nt * 16 + ln15;
        bb[nt] = bias[col];
        if (DO_LN) { gg[nt] = gamma[col]; be[nt] = beta[col]; }
    }
#pragma unroll
    for (int mt = 0; mt < 2; mt++)
#pragma unroll
        for (int nt = 0; nt < 8; nt++)
#pragma unroll
            for (int r = 0; r < 4; r++) acc[mt][nt][r] += bb[nt];

    float mu[2][4], rs[2][4];
    if (DO_LN) {
        // C/D layout: row = quad*4 + r, col = nt*16 + ln15. A row's 128 cols
        // live in the 16 lanes of one quad across the 8 nt tiles.
#pragma unroll
        for (int mt = 0; mt < 2; mt++)
#pragma unroll
            for (int r = 0; r < 4; r++) {
                float s = 0.f, s2 = 0.f;
#pragma unroll
                for (int nt = 0; nt < 8; nt++) {
                    float v = acc[mt][nt][r];
                    s += v; s2 += v * v;
                }
#pragma unroll
                for (int off = 1; off < 16; off <<= 1) {
                    s  += __shfl_xor(s,  off, 64);
                    s2 += __shfl_xor(s2, off, 64);
                }
                float m = s * (1.f / 128.f);
                mu[mt][r] = m;
                rs[mt][r] = rsqrtf(s2 * (1.f / 128.f) - m * m + EPS);
            }
    }

#pragma unroll
    for (int mt = 0; mt < 2; mt++)
#pragma unroll
        for (int nt = 0; nt < 8; nt++)
#pragma unroll
            for (int r = 0; r < 4; r++) {
                float v = acc[mt][nt][r];
                if (DO_LN) v = (v - mu[mt][r]) * rs[mt][r] * gg[nt] + be[nt];
                size_t o = (size_t)(m0 + wrow + mt * 16 + quad * 4 + r) * 128 + nt * 16 + ln15;
                if (OUT_SPLIT) {
                    unsigned int bits = __float_as_uint(v);
                    out_hi[o] = (unsigned short)(bits >> 16);
                    out_lo[o] = f2b_rne(v - __uint_as_float(bits & 0xffff0000u));
                } else {
                    outf[o] = v;
                }
            }
}

// =================== init slots + LN + q (one block per slot row) ============
__global__ __launch_bounds__(128) void init_lnq_kernel(
    const float* __restrict__ noise, const float* __restrict__ smu,
    const float* __restrict__ sls, const float* __restrict__ g_s,
    const float* __restrict__ b_s, const float* __restrict__ Wq,
    const float* __restrict__ bq, float* __restrict__ slots,
    float* __restrict__ q)
{
    __shared__ float s_l[128];
    __shared__ float red[4];
    const int row = blockIdx.x, tid = threadIdx.x;
    const int k = row % 3;
    float x = smu[k * 128 + tid] + expf(sls[k * 128 + tid]) * noise[row * 128 + tid];
    slots[row * 128 + tid] = x;

    float s = x, s2 = x * x;
#pragma unroll
    for (int off = 32; off >= 1; off >>= 1) {
        s += __shfl_down(s, off, 64); s2 += __shfl_down(s2, off, 64);
    }
    if ((tid & 63) == 0) { red[tid >> 6] = s; red[2 + (tid >> 6)] = s2; }
    __syncthreads();
    float S = red[0] + red[1], S2 = red[2] + red[3];
    float m = S * (1.f / 128.f);
    float r = rsqrtf(S2 * (1.f / 128.f) - m * m + EPS);
    s_l[tid] = (x - m) * r * g_s[tid] + b_s[tid];
    __syncthreads();

    const float4* wr = (const float4*)&Wq[(size_t)tid * 128];
    float a = bq[tid];
#pragma unroll 8
    for (int d4 = 0; d4 < 32; d4++) {
        float4 w = wr[d4];
        a += s_l[4 * d4] * w.x + s_l[4 * d4 + 1] * w.y
           + s_l[4 * d4 + 2] * w.z + s_l[4 * d4 + 3] * w.w;
    }
    q[row * 128 + tid] = a;
}

// ============ fused attention: logits -> softmax(K=3) -> partial updates =====
// fp32 k/v; per-chunk partial outputs (no atomics/memset).
__global__ __launch_bounds__(256) void attn_kernel(
    const float* __restrict__ q, const float* __restrict__ kbuf,
    const float* __restrict__ vbuf, float* __restrict__ upd_part,
    float* __restrict__ attn_out, int write_attn)
{
    __shared__ float q_l[3][128];
    __shared__ __align__(16) float kv[64][132];
    __shared__ float lg[3][64];
    __shared__ float w_l[3][64];
    const int b = blockIdx.y, chunk = blockIdx.x, n0 = chunk * 64, tid = threadIdx.x;

    for (int idx = tid; idx < 384; idx += 256)
        q_l[idx >> 7][idx & 127] = q[b * 384 + idx];

    const float4* kg = (const float4*)(kbuf + ((size_t)b * 1024 + n0) * 128);
    for (int idx = tid; idx < 2048; idx += 256) {
        int n = idx >> 5, c = (idx & 31) * 4;
        *(float4*)&kv[n][c] = kg[idx];
    }
    __syncthreads();

    { // logits: thread = (token n, quarter q4); all 256 threads active
        int n = tid >> 2, q4 = tid & 3;
        const float* kr = &kv[n][q4 * 32];
        const float* q0 = &q_l[0][q4 * 32];
        const float* q1 = &q_l[1][q4 * 32];
        const float* q2 = &q_l[2][q4 * 32];
        float p0 = 0.f, p1 = 0.f, p2 = 0.f;
#pragma unroll 8
        for (int i = 0; i < 32; i++) {
            float vv = kr[i];
            p0 += q0[i] * vv; p1 += q1[i] * vv; p2 += q2[i] * vv;
        }
        p0 += __shfl_xor(p0, 1, 64); p0 += __shfl_xor(p0, 2, 64);
        p1 += __shfl_xor(p1, 1, 64); p1 += __shfl_xor(p1, 2, 64);
        p2 += __shfl_xor(p2, 1, 64); p2 += __shfl_xor(p2, 2, 64);
        if (q4 == 0) {
            lg[0][n] = p0 * SCALE; lg[1][n] = p1 * SCALE; lg[2][n] = p2 * SCALE;
        }
    }
    __syncthreads();

    if (tid < 64) { // softmax over the 3 slots for token n=tid
        float l0 = lg[0][tid], l1 = lg[1][tid], l2 = lg[2][tid];
        float m = fmaxf(l0, fmaxf(l1, l2));
        float e0 = expf(l0 - m), e1 = expf(l1 - m), e2 = expf(l2 - m);
        float inv = 1.f / (e0 + e1 + e2);
        w_l[0][tid] = e0 * inv; w_l[1][tid] = e1 * inv; w_l[2][tid] = e2 * inv;
        if (write_attn) {
            attn_out[b * 3072 + n0 + tid]        = e0 * inv;
            attn_out[b * 3072 + 1024 + n0 + tid] = e1 * inv;
            attn_out[b * 3072 + 2048 + n0 + tid] = e2 * inv;
        }
    }
    const float4* vg = (const float4*)(vbuf + ((size_t)b * 1024 + n0) * 128);
    for (int idx = tid; idx < 2048; idx += 256) {
        int n = idx >> 5, c = (idx & 31) * 4;
        *(float4*)&kv[n][c] = vg[idx];
    }
    __syncthreads();

    if (tid < 128) {
        float p0 = 0.f, p1 = 0.f, p2 = 0.f;
#pragma unroll 8
        for (int n = 0; n < 64; n++) {
            float vv = kv[n][tid];
            p0 += w_l[0][n] * vv; p1 += w_l[1][n] * vv; p2 += w_l[2][n] * vv;
        }
        size_t base = (((size_t)b * 16 + chunk) * 3) * 128 + tid;
        upd_part[base]       = p0;
        upd_part[base + 128] = p1;
        upd_part[base + 256] = p2;
    }
}

// ====== fused GRU cell + LN + MLP residual + (LN_s + q for next iter) ========
__global__ __launch_bounds__(128) void gru_mlp_kernel(
    const float* __restrict__ slots_in, const float* __restrict__ upd_part,
    const float* __restrict__ Wih, const float* __restrict__ bih,
    const float* __restrict__ Whh, const float* __restrict__ bhh,
    const float* __restrict__ g_m, const float* __restrict__ b_m,
    const float* __restrict__ W1, const float* __restrict__ b1,
    const float* __restrict__ W2, const float* __restrict__ b2,
    const float* __restrict__ g_s, const float* __restrict__ b_s,
    const float* __restrict__ Wq, const float* __restrict__ bq,
    float* __restrict__ slots_out, float* __restrict__ q_out, int write_q)
{
    __shared__ float u_l[128], h_l[128], n_l[128], hid_l[256];
    __shared__ float red[4];
    const int row = blockIdx.x, tid = threadIdx.x;
    const int bb_ = row / 3, ss = row - bb_ * 3;

    float hprev = slots_in[row * 128 + tid];
    float u = 0.f;
    {
        const float* up = upd_part + (((size_t)bb_ * 16) * 3 + ss) * 128 + tid;
#pragma unroll
        for (int c = 0; c < 16; c++) u += up[(size_t)c * 384];
    }
    u_l[tid] = u;
    h_l[tid] = hprev;
    __syncthreads();

    float ir = bih[tid], iz = bih[128 + tid], in_ = bih[256 + tid];
    float hr = bhh[tid], hz = bhh[128 + tid], hn = bhh[256 + tid];
    const float4* wi0 = (const float4*)&Wih[(size_t)tid * 128];
    const float4* wi1 = (const float4*)&Wih[(size_t)(128 + tid) * 128];
    const float4* wi2 = (const float4*)&Wih[(size_t)(256 + tid) * 128];
    const float4* wh0 = (const float4*)&Whh[(size_t)tid * 128];
    const float4* wh1 = (const float4*)&Whh[(size_t)(128 + tid) * 128];
    const float4* wh2 = (const float4*)&Whh[(size_t)(256 + tid) * 128];
#pragma unroll 4
    for (int d4 = 0; d4 < 32; d4++) {
        float u0 = u_l[4 * d4], u1 = u_l[4 * d4 + 1], u2 = u_l[4 * d4 + 2], u3 = u_l[4 * d4 + 3];
        float h0 = h_l[4 * d4], h1 = h_l[4 * d4 + 1], h2 = h_l[4 * d4 + 2], h3 = h_l[4 * d4 + 3];
        float4 w;
        w = wi0[d4]; ir  += u0 * w.x + u1 * w.y + u2 * w.z + u3 * w.w;
        w = wi1[d4]; iz  += u0 * w.x + u1 * w.y + u2 * w.z + u3 * w.w;
        w = wi2[d4]; in_ += u0 * w.x + u1 * w.y + u2 * w.z + u3 * w.w;
        w = wh0[d4]; hr  += h0 * w.x + h1 * w.y + h2 * w.z + h3 * w.w;
        w = wh1[d4]; hz  += h0 * w.x + h1 * w.y + h2 * w.z + h3 * w.w;
        w = wh2[d4]; hn  += h0 * w.x + h1 * w.y + h2 * w.z + h3 * w.w;
    }
    float r = 1.f / (1.f + expf(-(ir + hr)));
    float z = 1.f / (1.f + expf(-(iz + hz)));
    float nn = tanhf(in_ + r * hn);
    float hnew = (1.f - z) * nn + z * hprev;

    float s = hnew, s2 = hnew * hnew;
#pragma unroll
    for (int off = 32; off >= 1; off >>= 1) {
        s += __shfl_down(s, off, 64); s2 += __shfl_down(s2, off, 64);
    }
    if ((tid & 63) == 0) { red[tid >> 6] = s; red[2 + (tid >> 6)] = s2; }
    __syncthreads();
    float S = red[0] + red[1], S2 = red[2] + red[3];
    float m1 = S * (1.f / 128.f);
    float r1 = rsqrtf(S2 * (1.f / 128.f) - m1 * m1 + EPS);
    n_l[tid] = (hnew - m1) * r1 * g_m[tid] + b_m[tid];
    __syncthreads();

    float a0 = b1[tid], a1 = b1[128 + tid];
    const float4* w1a = (const float4*)&W1[(size_t)tid * 128];
    const float4* w1b = (const float4*)&W1[(size_t)(128 + tid) * 128];
#pragma unroll 4
    for (int d4 = 0; d4 < 32; d4++) {
        float x0 = n_l[4 * d4], x1 = n_l[4 * d4 + 1], x2 = n_l[4 * d4 + 2], x3 = n_l[4 * d4 + 3];
        float4 wa = w1a[d4], wb = w1b[d4];
        a0 += x0 * wa.x + x1 * wa.y + x2 * wa.z + x3 * wa.w;
        a1 += x0 * wb.x + x1 * wb.y + x2 * wb.z + x3 * wb.w;
    }
    a0 = 0.5f * a0 * (1.f + erff(a0 * 0.70710678118654752f));
    a1 = 0.5f * a1 * (1.f + erff(a1 * 0.70710678118654752f));
    hid_l[tid] = a0; hid_l[128 + tid] = a1;
    __syncthreads();

    float o = b2[tid];
    const float4* w2r = (const float4*)&W2[(size_t)tid * 256];
#pragma unroll 4
    for (int d4 = 0; d4 < 64; d4++) {
        float4 w = w2r[d4];
        o += hid_l[4 * d4] * w.x + hid_l[4 * d4 + 1] * w.y
           + hid_l[4 * d4 + 2] * w.z + hid_l[4 * d4 + 3] * w.w;
    }
    float snew = hnew + o;
    slots_out[row * 128 + tid] = snew;

    if (write_q) {
        __syncthreads();
        float t = snew, t2 = snew * snew;
#pragma unroll
        for (int off = 32; off >= 1; off >>= 1) {
            t += __shfl_down(t, off, 64); t2 += __shfl_down(t2, off, 64);
        }
        if ((tid & 63) == 0) { red[tid >> 6] = t; red[2 + (tid >> 6)] = t2; }
        __syncthreads();
        float T = red[0] + red[1], T2 = red[2] + red[3];
        float m2 = T * (1.f / 128.f);
        float r2 = rsqrtf(T2 * (1.f / 128.f) - m2 * m2 + EPS);
        n_l[tid] = (snew - m2) * r2 * g_s[tid] + b_s[tid];
        __syncthreads();
        const float4* wr = (const float4*)&Wq[(size_t)tid * 128];
        float a = bq[tid];
#pragma unroll 8
        for (int d4 = 0; d4 < 32; d4++) {
            float4 w = wr[d4];
            a += n_l[4 * d4] * w.x + n_l[4 * d4 + 1] * w.y
               + n_l[4 * d4 + 2] * w.z + n_l[4 * d4 + 3] * w.w;
        }
        q_out[row * 128 + tid] = a;
    }
}

// ============================================================================
extern "C" void kernel_launch(void* const* d_in, const int* in_sizes, int n_in,
                              void* d_out, int out_size, void* d_ws, size_t ws_size,
                              hipStream_t stream)
{
    const float* patch   = (const float*)d_in[0];
    const float* noise   = (const float*)d_in[1];
    const float* slot_mu = (const float*)d_in[2];
    const float* slot_ls = (const float*)d_in[3];
    const float* Wp = (const float*)d_in[4];  const float* bp = (const float*)d_in[5];
    const float* g_in = (const float*)d_in[6]; const float* b_in = (const float*)d_in[7];
    const float* Wq = (const float*)d_in[8];  const float* bq = (const float*)d_in[9];
    const float* Wk = (const float*)d_in[10]; const float* bk = (const float*)d_in[11];
    const float* Wv = (const float*)d_in[12]; const float* bv = (const float*)d_in[13];
    const float* Wih = (const float*)d_in[14]; const float* bih = (const float*)d_in[15];
    const float* Whh = (const float*)d_in[16]; const float* bhh = (const float*)d_in[17];
    const float* g_s = (const float*)d_in[18]; const float* b_s = (const float*)d_in[19];
    const float* W1 = (const float*)d_in[20]; const float* b1 = (const float*)d_in[21];
    const float* W2 = (const float*)d_in[22]; const float* b2 = (const float*)d_in[23];
    const float* g_m = (const float*)d_in[24]; const float* b_m = (const float*)d_in[25];

    // ---- workspace layout (~201.6 MB) ----
    float* kbuf = (float*)d_ws;                                   // 16777216 f32
    float* vbuf = kbuf + 16777216;                                // 16777216 f32
    unsigned short* ln_hi = (unsigned short*)(vbuf + 16777216);   // 16777216 bf16
    unsigned short* ln_lo = ln_hi + 16777216;                     // 16777216 bf16
    unsigned short* w_hi  = ln_lo + 16777216;                     // 57344
    unsigned short* w_lo  = w_hi + 57344;                         // 57344
    unsigned short* wp_hi = w_hi,        * wp_lo = w_lo;
    unsigned short* wk_hi = w_hi + 24576,* wk_lo = w_lo + 24576;
    unsigned short* wv_hi = w_hi + 40960,* wv_lo = w_lo + 40960;
    // slots/q/partials alias the inputs(hi/lo) region — dead after GEMM2/3.
    float* slots = (float*)ln_hi;                                 // 49152 f32
    float* qbuf  = slots + 49152;                                 // 49152 f32
    float* part  = qbuf + 49152;                                  // 786432 f32

    float* out_slots = (float*)d_out;                             // (B,K,H)
    float* out_attn  = (float*)d_out + 49152;                     // (B,K,N)

    split_weights_kernel<<<224, 256, 0, stream>>>(Wp, Wk, Wv, w_hi, w_lo);

    // inputs = LN(patch @ Wp^T + bp) -> hi/lo bf16 planes (LN fused, fp32 math)
    gemm_split_kernel<192, false, true, true><<<1024, 256, 0, stream>>>(
        patch, nullptr, wp_hi, wp_lo, bp, g_in, b_in, nullptr, ln_hi, ln_lo);
    // k = inputs @ Wk^T + bk ; v = inputs @ Wv^T + bv  -> fp32
    gemm_split_kernel<128, true, false, false><<<1024, 256, 0, stream>>>(
        ln_hi, ln_lo, wk_hi, wk_lo, bk, nullptr, nullptr, kbuf, nullptr, nullptr);
    gemm_split_kernel<128, true, false, false><<<1024, 256, 0, stream>>>(
        ln_hi, ln_lo, wv_hi, wv_lo, bv, nullptr, nullptr, vbuf, nullptr, nullptr);

    // slots init + LN + q0 (after GEMMs: slots/q alias the inputs region)
    init_lnq_kernel<<<384, 128, 0, stream>>>(noise, slot_mu, slot_ls,
                                             g_s, b_s, Wq, bq, slots, qbuf);

    for (int it = 0; it < 3; it++) {
        attn_kernel<<<dim3(16, 128), 256, 0, stream>>>(
            qbuf, kbuf, vbuf, part, out_attn, it == 2 ? 1 : 0);
        gru_mlp_kernel<<<384, 128, 0, stream>>>(
            slots, part, Wih, bih, Whh, bhh, g_m, b_m, W1, b1, W2, b2,
            g_s, b_s, Wq, bq,
            (it == 2) ? out_slots : slots, qbuf, it == 2 ? 0 : 1);
    }
}